// Round 6
// baseline (1447.921 us; speedup 1.0000x reference)
//
#include <hip/hip_runtime.h>
#include <stdint.h>
#include <stddef.h>

#define K_DIM 4096
#define N_DIM 4096
#define BM 256
#define BN 256
#define BK 128                    // bytes of K per tile; 2 k-slices of 64
#define NT (K_DIM / BK)           // 32 K-tiles
#define REG_A (BM * BK)           // 32 KB  (A region within a slot)
#define REG_B (BN * BK)           // 32 KB
#define SLOT (REG_A + REG_B)      // 64 KB
#define LDS_BYTES (2 * SLOT)      // 128 KB double buffer
#define HALF 16384                // bytes per staged half (128 rows x 128 B)

typedef int v4i __attribute__((ext_vector_type(4)));
typedef uint32_t v4u __attribute__((ext_vector_type(4)));

__device__ __forceinline__ void load_lds16(const void* gp, void* lp) {
  __builtin_amdgcn_global_load_lds(
      (__attribute__((address_space(1))) void*)(uintptr_t)gp,
      (__attribute__((address_space(3))) void*)(uintptr_t)lp,
      16, 0, 0);
}

__device__ __forceinline__ uint32_t pack4(int a, int b, int c, int d) {
  return (uint32_t)(uint8_t)a | ((uint32_t)(uint8_t)b << 8) |
         ((uint32_t)(uint8_t)c << 16) | ((uint32_t)(uint8_t)d << 24);
}

// ---------------- Kernel 0: pack weight int32 -> int8 ----------------------
__global__ __launch_bounds__(256) void pack_w_kernel(
    const int4* __restrict__ w32, v4u* __restrict__ w8, int n16) {
  int i = blockIdx.x * 256 + threadIdx.x;
  if (i >= n16) return;
  int4 a = w32[i * 4 + 0], b = w32[i * 4 + 1], c = w32[i * 4 + 2], d = w32[i * 4 + 3];
  v4u o;
  o.x = pack4(a.x, a.y, a.z, a.w);
  o.y = pack4(b.x, b.y, b.z, b.w);
  o.z = pack4(c.x, c.y, c.z, c.w);
  o.w = pack4(d.x, d.y, d.z, d.w);
  w8[i] = o;
}

// ---------------- Kernel 1: quantize fp32 -> int8 --------------------------
// Exact fp32 division + RNE to match jnp.round(x / INPUT_SCALE).
__global__ __launch_bounds__(256) void quant_kernel(
    const float4* __restrict__ x, v4u* __restrict__ xq, int n16) {
  int i = blockIdx.x * 256 + threadIdx.x;
  if (i >= n16) return;
  v4u o;
#pragma unroll
  for (int j = 0; j < 4; ++j) {
    float4 v = x[i * 4 + j];
    float r0 = fminf(fmaxf(rintf(v.x / 0.05f), -128.f), 127.f);
    float r1 = fminf(fmaxf(rintf(v.y / 0.05f), -128.f), 127.f);
    float r2 = fminf(fmaxf(rintf(v.z / 0.05f), -128.f), 127.f);
    float r3 = fminf(fmaxf(rintf(v.w / 0.05f), -128.f), 127.f);
    o[j] = pack4((int)r0, (int)r1, (int)r2, (int)r3);
  }
  xq[i] = o;
}

// ---------------- Kernel 2: int8 GEMM, register-double-buffered tiles ------
// 256x256 tile, 8 waves (2M x 4N), wave tile 128x64; 64 MFMA/wave/tile.
//
// Round-5 post-mortem: one-barrier-per-tile still measured 5000 cy/tile =
// LDS reads (2304 cy/CU) + MFMA (2612 cy/SIMD) SERIAL. Cause: tile t's
// ds_reads may only start after the tile-top barrier (cross-wave DMA
// visibility), so every barrier restarts a port convoy with idle matrix
// pipes, then MFMA runs with an idle port.
//
// Fix: REGISTER double-buffering across tiles. Two named fragment sets
// (X/Y; rule 20 - no runtime indexing). At tile t's top, its fragments are
// already in registers (read during tile t-1), so MFMA issues immediately
// after the barrier; the 24 ds_reads for tile t+1 plus 8 DMAs for tile t+2
// drain through the LDS port UNDER the MFMA phase. lgkm(0) at tile end
// (port had a full MFMA phase to finish) doubles as the slot-race guard:
// reads of slot s complete before the barrier after which s is re-staged.
//
// Per-tile timeline (steady state, body for tile t):
//   vmcnt(0)            ; t+1's DMAs (issued in body t-1) drained -- free
//   barrier             ; all waves: slot reads done + t+1 visible
//   issue 8 DMA (t+2 -> slot t&1)  ; overwrites tile t's slot (frags in regs)
//   issue 24 ds_read (t+1 frags from slot (t+1)&1 -> other reg set)
//   sched_barrier       ; pin: all port work issued before MFMA block
//   64 MFMA on current reg set     ; port drains underneath
//   lgkm(0); sched_barrier (rule 18)
// Two-tile unrolled main loop (X=even tiles, Y=odd); peeled tail.
//
// Swizzle (verified, 0 conflicts): 16B chunk kv of row r at phys chunk
// kv ^ (r&7); staging permutes the per-lane GLOBAL source address
// (global_load_lds LDS dst is rigid). Stripe-interleaved halves kept
// (A by 64-row, B by 32-row stripes) -- same addresses as round 5.
//
// XCD swizzle: 512 blocks = 32 m x 16 n; 2 n-blocks per XCD.
__global__ __launch_bounds__(512, 1) void gemm_i8_kernel(
    const int8_t* __restrict__ A,     // [M, K] quantized activations
    const int8_t* __restrict__ B,     // [N, K] weight (packed int8)
    const float* __restrict__ bias,   // [N]
    float* __restrict__ C,            // [M, N]
    int M) {
  extern __shared__ __align__(16) int8_t lds[];

  const int tid  = threadIdx.x;
  const int lane = tid & 63;
  const int wave = tid >> 6;
  const int wm   = wave >> 2;   // 0..1  (128-row band)
  const int wn   = wave & 3;    // 0..3  (64-col band)
  const int quad = lane >> 4;
  const int lrow = lane & 15;
  const int k7   = lrow & 7;

  const int bid   = blockIdx.x;
  const int xcd   = bid & 7;
  const int slot  = bid >> 3;            // 0..63
  const int n_blk = xcd * 2 + (slot & 1);
  const int m_blk = slot >> 1;           // 0..31
  const int m0 = m_blk * BM;
  const int n0 = n_blk * BN;

  // Fragment read bases (byte offsets; add slot base at use).
  const int cs0  = (quad ^ k7) * 16;        // k-slice 0 chunk (swizzled)
  const int cs1  = ((4 + quad) ^ k7) * 16;  // k-slice 1 chunk
  const int aoff = (wm * 64 + lrow) * 128;          // A region, a-half 0
  const int boff = REG_A + (wn * 32 + lrow) * 128;  // B region, b-half 0

  // Staging source pointers (stripe-interleaved halves, inverse swizzle on
  // the global chunk). Chunk c = q*512 + tid; idx = c>>3 = row-in-half.
  const int8_t *pAe[2], *pAo[2], *pBe[2], *pBo[2];
  int dstc[2];
#pragma unroll
  for (int q = 0; q < 2; ++q) {
    int c   = q * 512 + tid;
    int idx = c >> 3;
    int lc  = (c & 7) ^ (idx & 7);
    int gA  = ((idx & 64) << 1) | (idx & 63);   // A-even stripe row
    int gB  = ((idx & 96) << 1) | (idx & 31);   // B-even stripe row
    pAe[q] = A + (size_t)(m0 + gA) * K_DIM + lc * 16;
    pAo[q] = A + (size_t)(m0 + gA + 64) * K_DIM + lc * 16;
    pBe[q] = B + (size_t)(n0 + gB) * K_DIM + lc * 16;
    pBo[q] = B + (size_t)(n0 + gB + 32) * K_DIM + lc * 16;
    dstc[q] = c * 16;
  }

#define ST_ALL(ws) { \
    load_lds16(pAe[0], lds + (ws) + dstc[0]); \
    load_lds16(pAe[1], lds + (ws) + dstc[1]); \
    load_lds16(pAo[0], lds + (ws) + HALF + dstc[0]); \
    load_lds16(pAo[1], lds + (ws) + HALF + dstc[1]); \
    load_lds16(pBe[0], lds + (ws) + REG_A + dstc[0]); \
    load_lds16(pBe[1], lds + (ws) + REG_A + dstc[1]); \
    load_lds16(pBo[0], lds + (ws) + REG_A + HALF + dstc[0]); \
    load_lds16(pBo[1], lds + (ws) + REG_A + HALF + dstc[1]); \
    pAe[0] += BK; pAe[1] += BK; pAo[0] += BK; pAo[1] += BK; \
    pBe[0] += BK; pBe[1] += BK; pBo[0] += BK; pBo[1] += BK; }
#define MFMA(d, x, y) d = __builtin_amdgcn_mfma_i32_16x16x64_i8(x, y, d, 0, 0, 0)

#define READ_FRAGS(S, base) { \
    _Pragma("unroll") for (int j = 0; j < 2; ++j) { \
      b0##S[j][0] = *(const v4i*)(lds + (base) + boff + j * 2048 + cs0); \
      b0##S[j][1] = *(const v4i*)(lds + (base) + boff + j * 2048 + cs1); \
      b1##S[j][0] = *(const v4i*)(lds + (base) + boff + HALF + j * 2048 + cs0); \
      b1##S[j][1] = *(const v4i*)(lds + (base) + boff + HALF + j * 2048 + cs1); \
    } \
    _Pragma("unroll") for (int i = 0; i < 4; ++i) { \
      a0##S[i][0] = *(const v4i*)(lds + (base) + aoff + i * 2048 + cs0); \
      a0##S[i][1] = *(const v4i*)(lds + (base) + aoff + i * 2048 + cs1); \
      a1##S[i][0] = *(const v4i*)(lds + (base) + aoff + HALF + i * 2048 + cs0); \
      a1##S[i][1] = *(const v4i*)(lds + (base) + aoff + HALF + i * 2048 + cs1); \
    } }

#define MFMA_ALL(S) { \
    _Pragma("unroll") for (int i = 0; i < 4; ++i) \
      _Pragma("unroll") for (int j = 0; j < 2; ++j) { \
        MFMA(acc[i][j],         a0##S[i][0], b0##S[j][0]); \
        MFMA(acc[i][j],         a0##S[i][1], b0##S[j][1]); \
        MFMA(acc[i][2 + j],     a0##S[i][0], b1##S[j][0]); \
        MFMA(acc[i][2 + j],     a0##S[i][1], b1##S[j][1]); \
        MFMA(acc[4 + i][j],     a1##S[i][0], b0##S[j][0]); \
        MFMA(acc[4 + i][j],     a1##S[i][1], b0##S[j][1]); \
        MFMA(acc[4 + i][2 + j], a1##S[i][0], b1##S[j][0]); \
        MFMA(acc[4 + i][2 + j], a1##S[i][1], b1##S[j][1]); \
      } }

// One tile body: CUR frags already in regs; prefetch NXT from rslot while
// MFMAing CUR; stage tile t+2 into wslot.
#define BODY(CUR, NXT, wslot, rslot) { \
    asm volatile("s_waitcnt vmcnt(0)" ::: "memory"); \
    __builtin_amdgcn_s_barrier(); \
    __builtin_amdgcn_sched_barrier(0); \
    ST_ALL(wslot); \
    READ_FRAGS(NXT, rslot); \
    __builtin_amdgcn_sched_barrier(0); \
    __builtin_amdgcn_s_setprio(1); \
    MFMA_ALL(CUR); \
    __builtin_amdgcn_s_setprio(0); \
    asm volatile("s_waitcnt lgkmcnt(0)" ::: "memory"); \
    __builtin_amdgcn_sched_barrier(0); }

  v4i a0X[4][2], a1X[4][2], b0X[2][2], b1X[2][2];
  v4i a0Y[4][2], a1Y[4][2], b0Y[2][2], b1Y[2][2];
  v4i acc[8][4] = {};

  // Prologue: stage tile 0 -> slot0; drain; sync; stage tile 1 -> slot1;
  // read tile 0 frags into X.
  ST_ALL(0);
  asm volatile("s_waitcnt vmcnt(0)" ::: "memory");
  __builtin_amdgcn_s_barrier();
  __builtin_amdgcn_sched_barrier(0);
  ST_ALL(SLOT);
  READ_FRAGS(X, 0);
  __builtin_amdgcn_sched_barrier(0);
  asm volatile("s_waitcnt lgkmcnt(0)" ::: "memory");
  __builtin_amdgcn_sched_barrier(0);

  // Main loop: tiles 2tt (X) and 2tt+1 (Y); stages tiles 2tt+2, 2tt+3.
#pragma unroll 1
  for (int tt = 0; tt < NT / 2 - 1; ++tt) {
    BODY(X, Y, 0, SLOT);      // tile 2tt:   DMA 2tt+2->slot0, read 2tt+1
    BODY(Y, X, SLOT, 0);      // tile 2tt+1: DMA 2tt+3->slot1, read 2tt+2
  }

  // Tail: tiles 30 (X, read 31) and 31 (Y); no staging.
  asm volatile("s_waitcnt vmcnt(0)" ::: "memory");
  __builtin_amdgcn_s_barrier();
  __builtin_amdgcn_sched_barrier(0);
  READ_FRAGS(Y, SLOT);
  __builtin_amdgcn_sched_barrier(0);
  __builtin_amdgcn_s_setprio(1);
  MFMA_ALL(X);
  __builtin_amdgcn_s_setprio(0);
  asm volatile("s_waitcnt lgkmcnt(0)" ::: "memory");
  __builtin_amdgcn_sched_barrier(0);
  __builtin_amdgcn_s_setprio(1);
  MFMA_ALL(Y);
  __builtin_amdgcn_s_setprio(0);

#undef ST_ALL
#undef MFMA
#undef READ_FRAGS
#undef MFMA_ALL
#undef BODY

  // Epilogue: y = 0.01 * acc + bias[n]
  // acc[p][jj]: row = wm*128 + (p>>2)*64 + (p&3)*16, col = wn*64 +
  // (jj>>1)*32 + (jj&1)*16. C/D frag: col = lane&15, row = quad*4 + r.
#pragma unroll
  for (int jj = 0; jj < 4; ++jj) {
    const int n = n0 + wn * 64 + (jj >> 1) * 32 + (jj & 1) * 16 + lrow;
    const float bn = bias[n];
#pragma unroll
    for (int p = 0; p < 8; ++p) {
      const int mb = m0 + wm * 128 + (p >> 2) * 64 + (p & 3) * 16 + quad * 4;
#pragma unroll
      for (int r = 0; r < 4; ++r)
        C[(size_t)(mb + r) * N_DIM + n] = 0.01f * (float)acc[p][jj][r] + bn;
    }
  }
}

extern "C" void kernel_launch(void* const* d_in, const int* in_sizes, int n_in,
                              void* d_out, int out_size, void* d_ws, size_t ws_size,
                              hipStream_t stream) {
  static bool inited = false;
  if (!inited) {
    (void)hipFuncSetAttribute(reinterpret_cast<const void*>(gemm_i8_kernel),
                              hipFuncAttributeMaxDynamicSharedMemorySize,
                              LDS_BYTES);
    inited = true;
  }

  const float* x    = (const float*)d_in[0];
  const int*   w32  = (const int*)d_in[1];   // harness stores int8 input as int32
  const float* bias = (const float*)d_in[2];
  float* out = (float*)d_out;
  const int M = in_sizes[0] / K_DIM;  // 8192

  int8_t* xq = (int8_t*)d_ws;                              // M*K
  int8_t* wq = (int8_t*)d_ws + (size_t)M * K_DIM;          // N*K

  const int nw16 = (N_DIM * K_DIM) / 16;
  pack_w_kernel<<<(nw16 + 255) / 256, 256, 0, stream>>>(
      (const int4*)w32, (v4u*)wq, nw16);

  const int n16 = (M * K_DIM) / 16;
  quant_kernel<<<(n16 + 255) / 256, 256, 0, stream>>>(
      (const float4*)x, (v4u*)xq, n16);

  const int nblocks = (M / BM) * (N_DIM / BN);  // 512
  gemm_i8_kernel<<<nblocks, 512, LDS_BYTES, stream>>>(xq, wq, bias, out, M);
}

// Round 7
// 398.353 us; speedup vs baseline: 3.6348x; 3.6348x over previous
//
#include <hip/hip_runtime.h>
#include <stdint.h>
#include <stddef.h>

#define K_DIM 4096
#define N_DIM 4096
#define BM 256
#define BN 256
#define BK 64                     // bytes of K per tile = one 16x16x64 k-slice
#define NT (K_DIM / BK)           // 64 K-tiles
#define SLOT_A (BM * BK)          // 16 KB
#define SLOT_B (BN * BK)          // 16 KB
#define SLOT (SLOT_A + SLOT_B)    // 32 KB
#define LDS_BYTES (3 * SLOT)      // 96 KB ring-3

typedef int v4i __attribute__((ext_vector_type(4)));
typedef uint32_t v4u __attribute__((ext_vector_type(4)));

__device__ __forceinline__ void load_lds16(const void* gp, void* lp) {
  __builtin_amdgcn_global_load_lds(
      (__attribute__((address_space(1))) void*)(uintptr_t)gp,
      (__attribute__((address_space(3))) void*)(uintptr_t)lp,
      16, 0, 0);
}

__device__ __forceinline__ uint32_t pack4(int a, int b, int c, int d) {
  return (uint32_t)(uint8_t)a | ((uint32_t)(uint8_t)b << 8) |
         ((uint32_t)(uint8_t)c << 16) | ((uint32_t)(uint8_t)d << 24);
}

// ---------------- Kernel 0: pack weight int32 -> int8 ----------------------
__global__ __launch_bounds__(256) void pack_w_kernel(
    const int4* __restrict__ w32, v4u* __restrict__ w8, int n16) {
  int i = blockIdx.x * 256 + threadIdx.x;
  if (i >= n16) return;
  int4 a = w32[i * 4 + 0], b = w32[i * 4 + 1], c = w32[i * 4 + 2], d = w32[i * 4 + 3];
  v4u o;
  o.x = pack4(a.x, a.y, a.z, a.w);
  o.y = pack4(b.x, b.y, b.z, b.w);
  o.z = pack4(c.x, c.y, c.z, c.w);
  o.w = pack4(d.x, d.y, d.z, d.w);
  w8[i] = o;
}

// ---------------- Kernel 1: quantize fp32 -> int8 --------------------------
// Exact fp32 division + RNE to match jnp.round(x / INPUT_SCALE).
__global__ __launch_bounds__(256) void quant_kernel(
    const float4* __restrict__ x, v4u* __restrict__ xq, int n16) {
  int i = blockIdx.x * 256 + threadIdx.x;
  if (i >= n16) return;
  v4u o;
#pragma unroll
  for (int j = 0; j < 4; ++j) {
    float4 v = x[i * 4 + j];
    float r0 = fminf(fmaxf(rintf(v.x / 0.05f), -128.f), 127.f);
    float r1 = fminf(fmaxf(rintf(v.y / 0.05f), -128.f), 127.f);
    float r2 = fminf(fmaxf(rintf(v.z / 0.05f), -128.f), 127.f);
    float r3 = fminf(fmaxf(rintf(v.w / 0.05f), -128.f), 127.f);
    o[j] = pack4((int)r0, (int)r1, (int)r2, (int)r3);
  }
  xq[i] = o;
}

// ---------------- Kernel 2: int8 GEMM, partial-reg-prefetch ring-3 ---------
// 256x256 tile, 8 waves (2M x 4N), wave tile 128x64. BK=64 B -> 32 MFMA per
// wave per body (8 m-frags x 4 n-frags).
//
// Round-6 post-mortem: full 2-set register dbuf (2x24 v4i = 192 VGPR) blew
// the 256 addressable-VGPR budget -> scratch spill (FETCH 12x, 1212 us).
// This version keeps the overlap idea at HALF the register freight:
//   - prefetch set (a0[4]+b[4] = 8 v4i), double-named X/Y (rule 20)
//   - a1[4] read and consumed IN-body (single shared set)
//   => persistent frags 20 v4i = 80 VGPR; acc[8][4] in AGPR.
// Body t (one barrier, one vmcnt(0), both behind ~1300 cy of MFMA):
//   issue 4 ds_read a1(t)      from slot t%3
//   issue 8 ds_read a0/b(t+1)  from slot (t+1)%3  (DMA'd body t-1, drained)
//   issue 4 DMA stage t+2  ->  slot (t+2)%3  (occupant t-1 fully read)
//   16 MFMA on a0/b (in regs since last body -- zero port wait at body top)
//   lgkm(8) -> a1 landed; 16 MFMA on a1
//   lgkm(0); vmcnt(0); barrier     (port had the whole MFMA phase to drain)
// Port (96 reads x 12cy + 256cy DMA ~ 1408) runs UNDER MFMA (1306) instead
// of serial with it (round-5: 5000 cy/body-pair equivalent).
//
// LDS swizzle (64-B rows, paired into 128-B LINES): line L holds rows
// 2L,2L+1; chunk-in-line c (0..7) stored at phys c ^ (L&7). Each frag
// ds_read's 64 lanes cover one contiguous 1 KB block's 64 chunks exactly
// once -> every bank exactly 8 words, balanced (round-2's naive mod-4
// swizzle did NOT have this property and conflicted). Staging applies the
// inverse permutation on per-lane GLOBAL source addresses
// (global_load_lds LDS dst is rigid: base + lane*16).
//
// XCD swizzle: 512 blocks = 32 m x 16 n; 2 n-blocks per XCD.
__global__ __launch_bounds__(512, 1) void gemm_i8_kernel(
    const int8_t* __restrict__ A,     // [M, K] quantized activations
    const int8_t* __restrict__ B,     // [N, K] weight (packed int8)
    const float* __restrict__ bias,   // [N]
    float* __restrict__ C,            // [M, N]
    int M) {
  extern __shared__ __align__(16) int8_t lds[];

  const int tid  = threadIdx.x;
  const int lane = tid & 63;
  const int wave = tid >> 6;
  const int wm   = wave >> 2;   // 0..1  (128-row band)
  const int wn   = wave & 3;    // 0..3  (64-col band)
  const int quad = lane >> 4;
  const int lrow = lane & 15;
  const int lr2  = lrow >> 1;

  const int bid   = blockIdx.x;
  const int xcd   = bid & 7;
  const int slot  = bid >> 3;            // 0..63
  const int n_blk = xcd * 2 + (slot & 1);
  const int m_blk = slot >> 1;           // 0..31
  const int m0 = m_blk * BM;
  const int n0 = n_blk * BN;

  // Fragment read bases. Row r at line r>>1 (128 B), sub-chunk
  // (r&1)*4 + quad, phys = lc ^ (line&7). Frag bases are multiples of 16
  // rows = 8 lines, so line&7 == lr2 for every fragment.
  const int swz16 = ((((lrow & 1) << 2) | quad) ^ lr2) << 4;
  const int aoff = (wm * 64 + lr2) * 128 + swz16;           // A region
  const int boff = SLOT_A + (wn * 32 + lr2) * 128 + swz16;  // B region
  // frag i/j adds i*1024 (8 lines).

  // Staging source pointers (inverse swizzle). Chunk c = q*512 + tid over
  // the 1024 16B-chunks of each region; line = c>>3, logical chunk-in-line
  // lc = (c&7)^(line&7); row = line*2 + (lc>>2), k-chunk = lc&3.
  const int8_t *pA[2], *pB[2];
  int dstc[2];
#pragma unroll
  for (int q = 0; q < 2; ++q) {
    int c    = q * 512 + tid;
    int line = c >> 3;
    int lc   = (c & 7) ^ (line & 7);
    int row  = (line << 1) | (lc >> 2);
    int kc   = lc & 3;
    pA[q] = A + (size_t)(m0 + row) * K_DIM + kc * 16;
    pB[q] = B + (size_t)(n0 + row) * K_DIM + kc * 16;
    dstc[q] = c * 16;
  }

#define STAGE(base) { \
    load_lds16(pA[0], lds + (base) + dstc[0]); \
    load_lds16(pA[1], lds + (base) + dstc[1]); \
    load_lds16(pB[0], lds + (base) + SLOT_A + dstc[0]); \
    load_lds16(pB[1], lds + (base) + SLOT_A + dstc[1]); \
    pA[0] += BK; pA[1] += BK; pB[0] += BK; pB[1] += BK; }

#define READ_PRE(S, base) { \
    _Pragma("unroll") for (int i = 0; i < 4; ++i) \
      a0##S[i] = *(const v4i*)(lds + (base) + aoff + i * 1024); \
    _Pragma("unroll") for (int j = 0; j < 4; ++j) \
      b##S[j] = *(const v4i*)(lds + (base) + boff + j * 1024); }

#define READ_A1(base) { \
    _Pragma("unroll") for (int i = 0; i < 4; ++i) \
      a1[i] = *(const v4i*)(lds + (base) + aoff + (4 + i) * 1024); }

#define MFMA(d, x, y) d = __builtin_amdgcn_mfma_i32_16x16x64_i8(x, y, d, 0, 0, 0)

#define MFMA_A0(S) { \
    _Pragma("unroll") for (int i = 0; i < 4; ++i) \
      _Pragma("unroll") for (int j = 0; j < 4; ++j) \
        MFMA(acc[i][j], a0##S[i], b##S[j]); }

#define MFMA_A1(S) { \
    _Pragma("unroll") for (int i = 0; i < 4; ++i) \
      _Pragma("unroll") for (int j = 0; j < 4; ++j) \
        MFMA(acc[4 + i][j], a1[i], b##S[j]); }

// Full body: CUR's a0/b already in regs; read a1(CUR) + prefetch NXT;
// stage t+2; overlap everything under the 32 MFMAs.
#define BODY_FULL(CUR, NXT) { \
    READ_A1(rs); \
    READ_PRE(NXT, ns); \
    STAGE(ws); \
    __builtin_amdgcn_sched_barrier(0); \
    __builtin_amdgcn_s_setprio(1); \
    MFMA_A0(CUR); \
    asm volatile("s_waitcnt lgkmcnt(8)" ::: "memory"); \
    __builtin_amdgcn_sched_barrier(0); \
    MFMA_A1(CUR); \
    __builtin_amdgcn_s_setprio(0); \
    asm volatile("s_waitcnt lgkmcnt(0) vmcnt(0)" ::: "memory"); \
    __builtin_amdgcn_s_barrier(); \
    __builtin_amdgcn_sched_barrier(0); }

#define ROT() { int _t = rs; rs = ns; ns = ws; ws = _t; }

  v4i a0X[4], bX[4], a0Y[4], bY[4], a1[4];
  v4i acc[8][4] = {};

  // Prologue: stage tiles 0,1 -> slots 0,1; drain; read tile-0 pre-frags.
  STAGE(0);
  STAGE(SLOT);
  asm volatile("s_waitcnt vmcnt(0)" ::: "memory");
  __builtin_amdgcn_s_barrier();
  __builtin_amdgcn_sched_barrier(0);
  READ_PRE(X, 0);
  asm volatile("s_waitcnt lgkmcnt(0)" ::: "memory");
  __builtin_amdgcn_sched_barrier(0);

  int rs = 0, ns = SLOT, ws = 2 * SLOT;

  // Bodies 0..61 (all with prefetch + stage), X/Y alternating.
#pragma unroll 1
  for (int tt = 0; tt < 31; ++tt) {
    BODY_FULL(X, Y); ROT();
    BODY_FULL(Y, X); ROT();
  }

  // Body 62 (X current): a1 + prefetch tile 63; no stage, no barrier needed.
  READ_A1(rs);
  READ_PRE(Y, ns);
  __builtin_amdgcn_sched_barrier(0);
  __builtin_amdgcn_s_setprio(1);
  MFMA_A0(X);
  asm volatile("s_waitcnt lgkmcnt(8)" ::: "memory");
  __builtin_amdgcn_sched_barrier(0);
  MFMA_A1(X);
  __builtin_amdgcn_s_setprio(0);
  ROT();

  // Body 63 (Y current): a1 only.
  READ_A1(rs);
  asm volatile("s_waitcnt lgkmcnt(0)" ::: "memory");
  __builtin_amdgcn_sched_barrier(0);
  __builtin_amdgcn_s_setprio(1);
  MFMA_A0(Y);
  MFMA_A1(Y);
  __builtin_amdgcn_s_setprio(0);

#undef STAGE
#undef READ_PRE
#undef READ_A1
#undef MFMA
#undef MFMA_A0
#undef MFMA_A1
#undef BODY_FULL
#undef ROT

  // Epilogue: y = 0.01 * acc + bias[n]
  // acc[i][j]: row = wm*128 + i*16, col = wn*64 + j*16.
  // C/D frag: col = lane&15, row = quad*4 + r.
#pragma unroll
  for (int j = 0; j < 4; ++j) {
    const int n = n0 + wn * 64 + j * 16 + lrow;
    const float bn = bias[n];
#pragma unroll
    for (int i = 0; i < 8; ++i) {
      const int mb = m0 + wm * 128 + i * 16 + quad * 4;
#pragma unroll
      for (int r = 0; r < 4; ++r)
        C[(size_t)(mb + r) * N_DIM + n] = 0.01f * (float)acc[i][j][r] + bn;
    }
  }
}

extern "C" void kernel_launch(void* const* d_in, const int* in_sizes, int n_in,
                              void* d_out, int out_size, void* d_ws, size_t ws_size,
                              hipStream_t stream) {
  static bool inited = false;
  if (!inited) {
    (void)hipFuncSetAttribute(reinterpret_cast<const void*>(gemm_i8_kernel),
                              hipFuncAttributeMaxDynamicSharedMemorySize,
                              LDS_BYTES);
    inited = true;
  }

  const float* x    = (const float*)d_in[0];
  const int*   w32  = (const int*)d_in[1];   // harness stores int8 input as int32
  const float* bias = (const float*)d_in[2];
  float* out = (float*)d_out;
  const int M = in_sizes[0] / K_DIM;  // 8192

  int8_t* xq = (int8_t*)d_ws;                              // M*K
  int8_t* wq = (int8_t*)d_ws + (size_t)M * K_DIM;          // N*K

  const int nw16 = (N_DIM * K_DIM) / 16;
  pack_w_kernel<<<(nw16 + 255) / 256, 256, 0, stream>>>(
      (const int4*)w32, (v4u*)wq, nw16);

  const int n16 = (M * K_DIM) / 16;
  quant_kernel<<<(n16 + 255) / 256, 256, 0, stream>>>(
      (const float4*)x, (v4u*)xq, n16);

  const int nblocks = (M / BM) * (N_DIM / BN);  // 512
  gemm_i8_kernel<<<nblocks, 512, LDS_BYTES, stream>>>(xq, wq, bias, out, M);
}